// Round 1
// baseline (1544.523 us; speedup 1.0000x reference)
//
#include <hip/hip_runtime.h>
#include <math.h>

#define NLEADS 61

// One block per (batch, lead). 256 threads.
// LDS: x slice (reused as h1p after conv1) + small weights + intermediates. ~45 KB.
__global__ __launch_bounds__(256, 3)
void lead_cnn_kernel(const float* __restrict__ x,
                     const float* __restrict__ w1g, const float* __restrict__ b1g,
                     const float* __restrict__ w2g, const float* __restrict__ b2g,
                     const float* __restrict__ w3g, const float* __restrict__ b3g,
                     const float* __restrict__ w4g, const float* __restrict__ b4g,
                     const float* __restrict__ fcwg, const float* __restrict__ fcbg,
                     float* __restrict__ preds)
{
    __shared__ __align__(16) float sx[8064];  // x (8000 floats) then h1p (8,16,63)=8064
    __shared__ float w1s[96];
    __shared__ float b1s[8];
    __shared__ float w2s[1536];
    __shared__ float b2s[16];
    __shared__ float b3s[32];
    __shared__ float sh2[1024];   // h2 pooled (16,4,16)
    __shared__ float sh3[256];    // h3 pooled (32,2,4)
    __shared__ float spart[256];  // conv4 partials
    __shared__ float shf[64];     // conv4 output
    __shared__ float slog[4];

    const int t = threadIdx.x;
    const int b = blockIdx.x;
    const int l = blockIdx.y;

    // ---- stage x (coalesced float4) + small weights/biases into LDS ----
    {
        const float4* xg4 = (const float4*)(x + ((size_t)b * NLEADS + l) * 8000);
        float4* sx4 = (float4*)sx;
        for (int i = t; i < 2000; i += 256) sx4[i] = xg4[i];
    }
    for (int i = t; i < 96;   i += 256) w1s[i] = w1g[l*96 + i];
    for (int i = t; i < 1536; i += 256) w2s[i] = w2g[l*1536 + i];
    if (t < 8)  b1s[t] = b1g[l*8 + t];
    if (t < 16) b2s[t] = b2g[l*16 + t];
    if (t < 32) b3s[t] = b3g[l*32 + t];
    __syncthreads();

    // ---- conv1 (8,1,3,4) stride(1,2) pad(1,2) + maxpool2 + relu -> (8,16,63) ----
    // 1008 spatial pool positions; each thread handles up to 4, all 8 oc each,
    // accumulating into registers so sx can be reused for h1p afterwards.
    float acc1[4][8];
    #pragma unroll
    for (int it = 0; it < 4; ++it) {
        const int item = t + it*256;        // up to 1023; reads stay clipped/in-range
        const int ph = item / 63;
        const int pw = item - ph*63;
        const int r0 = 2*ph - 1, c0 = 4*pw - 2;
        float xv[4][6];
        #pragma unroll
        for (int r = 0; r < 4; ++r) {
            const int ih = r0 + r;
            const bool rok = (ih >= 0) & (ih < 32);
            #pragma unroll
            for (int c = 0; c < 6; ++c) {
                const int iw = c0 + c;
                const bool ok = rok & (iw >= 0) & (iw < 250);
                xv[r][c] = ok ? sx[ih*250 + iw] : 0.f;
            }
        }
        #pragma unroll
        for (int oc = 0; oc < 8; ++oc) {
            float m = -INFINITY;
            #pragma unroll
            for (int dy = 0; dy < 2; ++dy)
            #pragma unroll
            for (int dx = 0; dx < 2; ++dx) {
                float s = 0.f;
                #pragma unroll
                for (int kh = 0; kh < 3; ++kh)
                #pragma unroll
                for (int kw = 0; kw < 4; ++kw)
                    s += w1s[oc*12 + kh*4 + kw] * xv[dy+kh][2*dx+kw];
                m = fmaxf(m, s);
            }
            acc1[it][oc] = fmaxf(m + b1s[oc], 0.f);
        }
    }
    __syncthreads();   // all x reads done; reuse sx for h1p
    #pragma unroll
    for (int it = 0; it < 4; ++it) {
        const int item = t + it*256;
        if (item < 1008) {
            #pragma unroll
            for (int oc = 0; oc < 8; ++oc)
                sx[oc*1008 + item] = acc1[it][oc];   // h1p[oc][ph][pw]
        }
    }
    __syncthreads();

    // ---- conv2 (16,8,4,3) stride(2,2) pad(1,1) + maxpool2 + relu -> (16,4,16) ----
    // 64 spatial pool positions x 4 oc-groups; oc-group is wave-uniform.
    {
        const int s  = t & 63;
        const int og = t >> 6;          // wave-uniform
        const int ph2 = s >> 4;         // 0..3
        const int pw2 = s & 15;         // 0..15
        const int r0 = 4*ph2 - 1, c0 = 4*pw2 - 1;
        float acc2[4][4];
        #pragma unroll
        for (int ol = 0; ol < 4; ++ol)
            #pragma unroll
            for (int q = 0; q < 4; ++q) acc2[ol][q] = 0.f;
        #pragma unroll 1
        for (int ic = 0; ic < 8; ++ic) {
            float xv[6][5];
            #pragma unroll
            for (int r = 0; r < 6; ++r) {
                const int ih = r0 + r;
                const bool rok = (ih >= 0) & (ih < 16);
                #pragma unroll
                for (int c = 0; c < 5; ++c) {
                    const int iw = c0 + c;
                    const bool ok = rok & (iw >= 0) & (iw < 63);
                    xv[r][c] = ok ? sx[ic*1008 + ih*63 + iw] : 0.f;
                }
            }
            #pragma unroll
            for (int ol = 0; ol < 4; ++ol) {
                const int oc = og*4 + ol;
                const float* wp = &w2s[oc*96 + ic*12];   // [kh(4)][kw(3)]
                #pragma unroll
                for (int dy = 0; dy < 2; ++dy)
                #pragma unroll
                for (int dx = 0; dx < 2; ++dx) {
                    float s2 = acc2[ol][dy*2+dx];
                    #pragma unroll
                    for (int kh = 0; kh < 4; ++kh)
                    #pragma unroll
                    for (int kw = 0; kw < 3; ++kw)
                        s2 += wp[kh*3+kw] * xv[2*dy+kh][2*dx+kw];
                    acc2[ol][dy*2+dx] = s2;
                }
            }
        }
        #pragma unroll
        for (int ol = 0; ol < 4; ++ol) {
            const int oc = og*4 + ol;
            float m = fmaxf(fmaxf(acc2[ol][0], acc2[ol][1]),
                            fmaxf(acc2[ol][2], acc2[ol][3]));
            sh2[oc*64 + s] = fmaxf(m + b2s[oc], 0.f);    // h2p[oc][ph2][pw2]
        }
    }
    __syncthreads();

    // ---- conv3 (32,16,3,4) stride(1,2) pad(1,1) + maxpool2 + relu -> (32,2,4) ----
    // 8 spatial pool positions x 32 oc = 256 work items, one per thread.
    {
        const int oc  = t >> 3;     // 0..31
        const int s   = t & 7;
        const int ph3 = s >> 2;     // 0..1
        const int pw3 = s & 3;      // 0..3
        const int r0 = 2*ph3 - 1, c0 = 4*pw3 - 1;
        float acc3[4] = {0.f, 0.f, 0.f, 0.f};
        const float* w3l = w3g + (size_t)l*6144 + oc*192;
        #pragma unroll 1
        for (int ic = 0; ic < 16; ++ic) {
            float xv[4][6];
            #pragma unroll
            for (int r = 0; r < 4; ++r) {
                const int ih = r0 + r;
                const bool rok = (ih >= 0) & (ih < 4);
                #pragma unroll
                for (int c = 0; c < 6; ++c) {
                    const int iw = c0 + c;
                    const bool ok = rok & (iw >= 0) & (iw < 16);
                    xv[r][c] = ok ? sh2[ic*64 + ih*16 + iw] : 0.f;
                }
            }
            const float4* wv = (const float4*)(w3l + ic*12);  // 12 floats, 16B-aligned
            const float4 wa = wv[0], wb = wv[1], wc = wv[2];
            const float w[12] = {wa.x,wa.y,wa.z,wa.w, wb.x,wb.y,wb.z,wb.w,
                                 wc.x,wc.y,wc.z,wc.w};
            #pragma unroll
            for (int dy = 0; dy < 2; ++dy)
            #pragma unroll
            for (int dx = 0; dx < 2; ++dx) {
                float s3 = acc3[dy*2+dx];
                #pragma unroll
                for (int kh = 0; kh < 3; ++kh)
                #pragma unroll
                for (int kw = 0; kw < 4; ++kw)
                    s3 += w[kh*4+kw] * xv[dy+kh][2*dx+kw];
                acc3[dy*2+dx] = s3;
            }
        }
        float m = fmaxf(fmaxf(acc3[0], acc3[1]), fmaxf(acc3[2], acc3[3]));
        sh3[oc*8 + s] = fmaxf(m + b3s[oc], 0.f);   // h3p[oc][kh][kw] ready for conv4
    }
    __syncthreads();

    // ---- conv4 (64,32,2,4) VALID -> (64,) ; split ic over 4 partials/oc ----
    {
        const int oc   = t >> 2;    // 0..63
        const int part = t & 3;     // 0..3 (8 ic each)
        const float4* w4v = (const float4*)(w4g + (size_t)l*16384 + oc*256 + part*64);
        float s4 = 0.f;
        #pragma unroll
        for (int j = 0; j < 8; ++j) {
            const float4 wa = w4v[j*2], wb = w4v[j*2+1];
            const float* xx = &sh3[(part*8 + j)*8];
            s4 += wa.x*xx[0] + wa.y*xx[1] + wa.z*xx[2] + wa.w*xx[3]
                + wb.x*xx[4] + wb.y*xx[5] + wb.z*xx[6] + wb.w*xx[7];
        }
        spart[part*64 + oc] = s4;
    }
    __syncthreads();
    if (t < 64)
        shf[t] = spart[t] + spart[64+t] + spart[128+t] + spart[192+t] + b4g[l*64 + t];
    __syncthreads();

    // ---- FC (3x64) + softmax ----
    if (t < 3) {
        const float* fw = fcwg + l*192 + t*64;
        float s = fcbg[l*3 + t];
        #pragma unroll
        for (int i = 0; i < 64; ++i) s += fw[i] * shf[i];
        slog[t] = s;
    }
    __syncthreads();
    if (t == 0) {
        const float a0 = slog[0], a1 = slog[1], a2 = slog[2];
        const float m = fmaxf(a0, fmaxf(a1, a2));
        const float e0 = expf(a0-m), e1 = expf(a1-m), e2 = expf(a2-m);
        const float inv = 1.f / (e0 + e1 + e2);
        float* pr = preds + ((size_t)b * NLEADS + l) * 3;
        pr[0] = e0*inv; pr[1] = e1*inv; pr[2] = e2*inv;
    }
}

// Cross-lead multiplicative fusion loss. One thread per (b, class).
__global__ void fusion_loss_kernel(const float* __restrict__ preds,
                                   float* __restrict__ out, int B)
{
    const int idx = blockIdx.x * blockDim.x + threadIdx.x;
    if (idx >= B*3) return;
    const int b = idx / 3;
    const int c = idx - 3*b;
    const float* p = preds + (size_t)b * (NLEADS*3) + c;
    float prod = 1.f;
    for (int j = 0; j < NLEADS; ++j) prod *= (1.f - p[j*3]);
    const float be = 2.0f / 60.0f;
    float loss = 0.f;
    for (int j = 0; j < NLEADS; ++j) {
        const float pj = p[j*3];
        loss += powf(prod / (1.f - pj), be) * logf(pj);
    }
    out[idx] = -loss;
}

extern "C" void kernel_launch(void* const* d_in, const int* in_sizes, int n_in,
                              void* d_out, int out_size, void* d_ws, size_t ws_size,
                              hipStream_t stream)
{
    const float* x   = (const float*)d_in[0];
    const float* w1  = (const float*)d_in[1];
    const float* b1  = (const float*)d_in[2];
    const float* w2  = (const float*)d_in[3];
    const float* b2  = (const float*)d_in[4];
    const float* w3  = (const float*)d_in[5];
    const float* b3  = (const float*)d_in[6];
    const float* w4  = (const float*)d_in[7];
    const float* b4  = (const float*)d_in[8];
    const float* fcw = (const float*)d_in[9];
    const float* fcb = (const float*)d_in[10];

    const int B = in_sizes[0] / (NLEADS * 32 * 250);   // 128
    float* preds = (float*)d_ws;                        // B*61*3 floats

    dim3 grid(B, NLEADS);
    hipLaunchKernelGGL(lead_cnn_kernel, grid, dim3(256), 0, stream,
                       x, w1, b1, w2, b2, w3, b3, w4, b4, fcw, fcb, preds);

    const int total = B * 3;
    hipLaunchKernelGGL(fusion_loss_kernel, dim3((total + 255) / 256), dim3(256),
                       0, stream, preds, (float*)d_out, B);
}

// Round 2
// 772.844 us; speedup vs baseline: 1.9985x; 1.9985x over previous
//
#include <hip/hip_runtime.h>
#include <math.h>
#include <utility>

#define NLEADS 61

// Guaranteed-unroll helper: indices become compile-time constants, so local
// arrays are SROA'd into registers (no scratch).
template <int... Is, typename F>
__device__ __forceinline__ void sf_(std::integer_sequence<int, Is...>, F&& f) {
    (f(std::integral_constant<int, Is>{}), ...);
}
template <int N, typename F>
__device__ __forceinline__ void static_for(F&& f) {
    sf_(std::make_integer_sequence<int, N>{}, (F&&)f);
}

// One block per (batch, lead). 256 threads.
__global__ __launch_bounds__(256, 3)
void lead_cnn_kernel(const float* __restrict__ x,
                     const float* __restrict__ w1g, const float* __restrict__ b1g,
                     const float* __restrict__ w2g, const float* __restrict__ b2g,
                     const float* __restrict__ w3g, const float* __restrict__ b3g,
                     const float* __restrict__ w4g, const float* __restrict__ b4g,
                     const float* __restrict__ fcwg, const float* __restrict__ fcbg,
                     float* __restrict__ preds)
{
    __shared__ __align__(16) float sx[8064];  // x (8000 floats), reused as h1p (8,16,63)
    __shared__ float w1s[96];
    __shared__ float b1s[8];
    __shared__ float w2s[1536];
    __shared__ float b2s[16];
    __shared__ float b3s[32];
    __shared__ float sh2[1024];   // h2 pooled (16,4,16)
    __shared__ float sh3[256];    // h3 pooled (32,2,4)
    __shared__ float spart[256];  // conv4 partials
    __shared__ float shf[64];     // conv4 output
    __shared__ float slog[4];

    const int t = threadIdx.x;
    const int b = blockIdx.x;
    const int l = blockIdx.y;

    // ---- stage x (coalesced float4) + small weights/biases into LDS ----
    {
        const float4* xg4 = (const float4*)(x + ((size_t)b * NLEADS + l) * 8000);
        float4* sx4 = (float4*)sx;
        for (int i = t; i < 2000; i += 256) sx4[i] = xg4[i];
    }
    for (int i = t; i < 96;   i += 256) w1s[i] = w1g[l*96 + i];
    for (int i = t; i < 1536; i += 256) w2s[i] = w2g[l*1536 + i];
    if (t < 8)  b1s[t] = b1g[l*8 + t];
    if (t < 16) b2s[t] = b2g[l*16 + t];
    if (t < 32) b3s[t] = b3g[l*32 + t];
    __syncthreads();

    // ---- conv1 (8,1,3,4) stride(1,2) pad(1,2) + maxpool2 + relu -> (8,16,63) ----
    float acc1[32];   // [it*8+oc], constant-indexed only
    static_for<4>([&](auto IT) {
        constexpr int it = IT.value;
        const int item = t + it*256;         // up to 1023; OOB lanes compute garbage, not stored
        const int ph = item / 63;
        const int pw = item - ph*63;
        const int r0 = 2*ph - 1, c0 = 4*pw - 2;
        float xv[24];                        // [r*6+c], constant-indexed only
        static_for<4>([&](auto R) {
            constexpr int r = R.value;
            const int ih = r0 + r;
            const bool rok = (ih >= 0) & (ih < 32);
            static_for<6>([&](auto C) {
                constexpr int c = C.value;
                const int iw = c0 + c;
                const bool ok = rok & (iw >= 0) & (iw < 250);
                const int idx = ok ? (ih*250 + iw) : 0;   // clamped, always in-bounds
                const float v = sx[idx];
                xv[r*6 + c] = ok ? v : 0.f;
            });
        });
        static_for<8>([&](auto OC) {
            constexpr int oc = OC.value;
            float m = -3.0e38f;
            static_for<2>([&](auto DY) {
                constexpr int dy = DY.value;
                static_for<2>([&](auto DX) {
                    constexpr int dx = DX.value;
                    float s = 0.f;
                    static_for<3>([&](auto KH) {
                        constexpr int kh = KH.value;
                        static_for<4>([&](auto KW) {
                            constexpr int kw = KW.value;
                            s += w1s[oc*12 + kh*4 + kw] * xv[(dy+kh)*6 + 2*dx+kw];
                        });
                    });
                    m = fmaxf(m, s);
                });
            });
            acc1[it*8 + oc] = fmaxf(m + b1s[oc], 0.f);
        });
    });
    __syncthreads();   // all x reads done; reuse sx for h1p
    static_for<4>([&](auto IT) {
        constexpr int it = IT.value;
        const int item = t + it*256;
        if (item < 1008) {
            static_for<8>([&](auto OC) {
                constexpr int oc = OC.value;
                sx[oc*1008 + item] = acc1[it*8 + oc];   // h1p[oc][ph][pw]
            });
        }
    });
    __syncthreads();

    // ---- conv2 (16,8,4,3) stride(2,2) pad(1,1) + maxpool2 + relu -> (16,4,16) ----
    {
        const int s  = t & 63;
        const int og = t >> 6;          // wave-uniform
        const int ph2 = s >> 4;
        const int pw2 = s & 15;
        const int r0 = 4*ph2 - 1, c0 = 4*pw2 - 1;
        float acc2[16];                 // [ol*4 + dy*2+dx]
        static_for<16>([&](auto I) { acc2[I.value] = 0.f; });
        for (int ic = 0; ic < 8; ++ic) {
            float xv[30];               // [r*5+c]
            static_for<6>([&](auto R) {
                constexpr int r = R.value;
                const int ih = r0 + r;
                const bool rok = (ih >= 0) & (ih < 16);
                static_for<5>([&](auto C) {
                    constexpr int c = C.value;
                    const int iw = c0 + c;
                    const bool ok = rok & (iw >= 0) & (iw < 63);
                    const int idx = ok ? (ic*1008 + ih*63 + iw) : 0;
                    const float v = sx[idx];
                    xv[r*5 + c] = ok ? v : 0.f;
                });
            });
            static_for<4>([&](auto OL) {
                constexpr int ol = OL.value;
                const int oc = og*4 + ol;
                const float* wp = &w2s[oc*96 + ic*12];   // [kh(4)][kw(3)]
                static_for<2>([&](auto DY) {
                    constexpr int dy = DY.value;
                    static_for<2>([&](auto DX) {
                        constexpr int dx = DX.value;
                        float s2 = acc2[ol*4 + dy*2+dx];
                        static_for<4>([&](auto KH) {
                            constexpr int kh = KH.value;
                            static_for<3>([&](auto KW) {
                                constexpr int kw = KW.value;
                                s2 += wp[kh*3+kw] * xv[(2*dy+kh)*5 + 2*dx+kw];
                            });
                        });
                        acc2[ol*4 + dy*2+dx] = s2;
                    });
                });
            });
        }
        static_for<4>([&](auto OL) {
            constexpr int ol = OL.value;
            const int oc = og*4 + ol;
            const float m = fmaxf(fmaxf(acc2[ol*4+0], acc2[ol*4+1]),
                                  fmaxf(acc2[ol*4+2], acc2[ol*4+3]));
            sh2[oc*64 + s] = fmaxf(m + b2s[oc], 0.f);    // h2p[oc][ph2][pw2]
        });
    }
    __syncthreads();

    // ---- conv3 (32,16,3,4) stride(1,2) pad(1,1) + maxpool2 + relu -> (32,2,4) ----
    {
        const int oc  = t >> 3;
        const int s   = t & 7;
        const int ph3 = s >> 2;
        const int pw3 = s & 3;
        const int r0 = 2*ph3 - 1, c0 = 4*pw3 - 1;
        float acc3[4] = {0.f, 0.f, 0.f, 0.f};
        const float* w3l = w3g + (size_t)l*6144 + oc*192;
        for (int ic = 0; ic < 16; ++ic) {
            float xv[24];               // [r*6+c]
            static_for<4>([&](auto R) {
                constexpr int r = R.value;
                const int ih = r0 + r;
                const bool rok = (ih >= 0) & (ih < 4);
                static_for<6>([&](auto C) {
                    constexpr int c = C.value;
                    const int iw = c0 + c;
                    const bool ok = rok & (iw >= 0) & (iw < 16);
                    const int idx = ok ? (ic*64 + ih*16 + iw) : 0;
                    const float v = sh2[idx];
                    xv[r*6 + c] = ok ? v : 0.f;
                });
            });
            const float4* wv = (const float4*)(w3l + ic*12);
            const float4 wa = wv[0], wb = wv[1], wc = wv[2];
            float w[12];
            w[0]=wa.x; w[1]=wa.y; w[2]=wa.z; w[3]=wa.w;
            w[4]=wb.x; w[5]=wb.y; w[6]=wb.z; w[7]=wb.w;
            w[8]=wc.x; w[9]=wc.y; w[10]=wc.z; w[11]=wc.w;
            static_for<2>([&](auto DY) {
                constexpr int dy = DY.value;
                static_for<2>([&](auto DX) {
                    constexpr int dx = DX.value;
                    float s3 = acc3[dy*2+dx];
                    static_for<3>([&](auto KH) {
                        constexpr int kh = KH.value;
                        static_for<4>([&](auto KW) {
                            constexpr int kw = KW.value;
                            s3 += w[kh*4+kw] * xv[(dy+kh)*6 + 2*dx+kw];
                        });
                    });
                    acc3[dy*2+dx] = s3;
                });
            });
        }
        const float m = fmaxf(fmaxf(acc3[0], acc3[1]), fmaxf(acc3[2], acc3[3]));
        sh3[oc*8 + s] = fmaxf(m + b3s[oc], 0.f);   // h3p[oc][kh][kw]
    }
    __syncthreads();

    // ---- conv4 (64,32,2,4) VALID -> (64,) ----
    {
        const int oc   = t >> 2;
        const int part = t & 3;
        const float4* w4v = (const float4*)(w4g + (size_t)l*16384 + oc*256 + part*64);
        float s4 = 0.f;
        static_for<8>([&](auto J) {
            constexpr int j = J.value;
            const float4 wa = w4v[j*2], wb = w4v[j*2+1];
            const float* xx = &sh3[(part*8 + j)*8];
            s4 += wa.x*xx[0] + wa.y*xx[1] + wa.z*xx[2] + wa.w*xx[3]
                + wb.x*xx[4] + wb.y*xx[5] + wb.z*xx[6] + wb.w*xx[7];
        });
        spart[part*64 + oc] = s4;
    }
    __syncthreads();
    if (t < 64)
        shf[t] = spart[t] + spart[64+t] + spart[128+t] + spart[192+t] + b4g[l*64 + t];
    __syncthreads();

    // ---- FC (3x64) + softmax ----
    if (t < 3) {
        const float* fw = fcwg + l*192 + t*64;
        float s = fcbg[l*3 + t];
        static_for<64>([&](auto I) { s += fw[I.value] * shf[I.value]; });
        slog[t] = s;
    }
    __syncthreads();
    if (t == 0) {
        const float a0 = slog[0], a1 = slog[1], a2 = slog[2];
        const float m = fmaxf(a0, fmaxf(a1, a2));
        const float e0 = expf(a0-m), e1 = expf(a1-m), e2 = expf(a2-m);
        const float inv = 1.f / (e0 + e1 + e2);
        float* pr = preds + ((size_t)b * NLEADS + l) * 3;
        pr[0] = e0*inv; pr[1] = e1*inv; pr[2] = e2*inv;
    }
}

// Cross-lead multiplicative fusion loss. One thread per (b, class).
__global__ void fusion_loss_kernel(const float* __restrict__ preds,
                                   float* __restrict__ out, int B)
{
    const int idx = blockIdx.x * blockDim.x + threadIdx.x;
    if (idx >= B*3) return;
    const int b = idx / 3;
    const int c = idx - 3*b;
    const float* p = preds + (size_t)b * (NLEADS*3) + c;
    float S = 0.f;                         // log prod(1-pj)
    for (int j = 0; j < NLEADS; ++j) S += logf(1.f - p[j*3]);
    const float be = 2.0f / 60.0f;
    float loss = 0.f;
    for (int j = 0; j < NLEADS; ++j) {
        const float pj = p[j*3];
        loss += expf(be * (S - logf(1.f - pj))) * logf(pj);
    }
    out[idx] = -loss;
}

extern "C" void kernel_launch(void* const* d_in, const int* in_sizes, int n_in,
                              void* d_out, int out_size, void* d_ws, size_t ws_size,
                              hipStream_t stream)
{
    const float* x   = (const float*)d_in[0];
    const float* w1  = (const float*)d_in[1];
    const float* b1  = (const float*)d_in[2];
    const float* w2  = (const float*)d_in[3];
    const float* b2  = (const float*)d_in[4];
    const float* w3  = (const float*)d_in[5];
    const float* b3  = (const float*)d_in[6];
    const float* w4  = (const float*)d_in[7];
    const float* b4  = (const float*)d_in[8];
    const float* fcw = (const float*)d_in[9];
    const float* fcb = (const float*)d_in[10];

    const int B = in_sizes[0] / (NLEADS * 32 * 250);   // 128
    float* preds = (float*)d_ws;                        // B*61*3 floats

    dim3 grid(B, NLEADS);
    hipLaunchKernelGGL(lead_cnn_kernel, grid, dim3(256), 0, stream,
                       x, w1, b1, w2, b2, w3, b3, w4, b4, fcw, fcb, preds);

    const int total = B * 3;
    hipLaunchKernelGGL(fusion_loss_kernel, dim3((total + 255) / 256), dim3(256),
                       0, stream, preds, (float*)d_out, B);
}